// Round 2
// 1190.071 us; speedup vs baseline: 1.2292x; 1.2292x over previous
//
#include <hip/hip_runtime.h>
#include <stdint.h>

#define NNODES 50000
#define NEDGES 1600000
#define NB     16384
#define HD     128
#define COMBW  384

typedef unsigned short u16;
typedef __bf16 bf16x8 __attribute__((ext_vector_type(8)));
typedef float  f32x4  __attribute__((ext_vector_type(4)));

__device__ __forceinline__ float b2f(u16 u){
    union { unsigned int i; float f; } v; v.i = ((unsigned int)u) << 16; return v.f;
}
__device__ __forceinline__ u16 f2b(float f){
    union { float f; unsigned int i; } v; v.f = f;
    unsigned int x = v.i;
    unsigned int r = (x + 0x7fffu + ((x >> 16) & 1u)) >> 16;
    return (u16)r;
}
// input f32 values are bf16-quantized -> truncation to high u16 is exact
__device__ __forceinline__ bf16x8 pack8(const float* __restrict__ p){
    uint4 a = *(const uint4*)p;
    uint4 b = *(const uint4*)(p + 4);
    union { u16 s[8]; bf16x8 v; } u;
    u.s[0] = (u16)(a.x >> 16); u.s[1] = (u16)(a.y >> 16);
    u.s[2] = (u16)(a.z >> 16); u.s[3] = (u16)(a.w >> 16);
    u.s[4] = (u16)(b.x >> 16); u.s[5] = (u16)(b.y >> 16);
    u.s[6] = (u16)(b.z >> 16); u.s[7] = (u16)(b.w >> 16);
    return u.v;
}

// ---------------- K0: user/item embedding gather (f32 -> f32 copy) ----------
__global__ void k_gather(const int* __restrict__ uid, const int* __restrict__ iid,
                         const float* __restrict__ utab, const float* __restrict__ itab,
                         float* __restrict__ out){
    int i = blockIdx.x * blockDim.x + threadIdx.x;   // 8 elements per thread
    const int total = 2 * NB * HD / 8;
    if (i >= total) return;
    int e8 = i * 8;
    const float* p;
    if (e8 < NB * HD) {
        int row = e8 >> 7, c = e8 & 127;
        p = utab + (size_t)uid[row] * HD + c;
    } else {
        int e2 = e8 - NB * HD;
        int row = e2 >> 7, c = e2 & 127;
        p = itab + (size_t)iid[row] * HD + c;
    }
    *(uint4*)(out + e8)     = *(const uint4*)p;
    *(uint4*)(out + e8 + 4) = *(const uint4*)(p + 4);
}

// ---------------- K1: x = relu(feat @ W^T + b), [NNODES, 32] f32 ----------------
__global__ __launch_bounds__(256) void k_feat(const float* __restrict__ feat, int K,
                                              const float* __restrict__ W,
                                              const float* __restrict__ bias,
                                              float* __restrict__ xout){
    int wave = threadIdx.x >> 6, lane = threadIdx.x & 63;
    int quad = lane >> 4, m = lane & 15;
    int row0 = blockIdx.x * 64 + wave * 16;
    int arow = row0 + m; if (arow >= NNODES) arow = NNODES - 1;
    const float* ap  = feat + (size_t)arow * K + quad * 8;
    const float* bp0 = W + (size_t)m        * K + quad * 8;
    const float* bp1 = W + (size_t)(m + 16) * K + quad * 8;
    f32x4 c0 = {0.f,0.f,0.f,0.f}, c1 = {0.f,0.f,0.f,0.f};
    for (int k = 0; k < K; k += 32){
        bf16x8 a  = pack8(ap  + k);
        bf16x8 b0 = pack8(bp0 + k);
        bf16x8 b1 = pack8(bp1 + k);
        c0 = __builtin_amdgcn_mfma_f32_16x16x32_bf16(a, b0, c0, 0, 0, 0);
        c1 = __builtin_amdgcn_mfma_f32_16x16x32_bf16(a, b1, c1, 0, 0, 0);
    }
    float bv0 = bias[m], bv1 = bias[m + 16];
    #pragma unroll
    for (int i = 0; i < 4; i++){
        int r = row0 + quad * 4 + i;
        if (r < NNODES){
            float v0 = c0[i] + bv0; v0 = v0 > 0.f ? v0 : 0.f;
            float v1 = c1[i] + bv1; v1 = v1 > 0.f ? v1 : 0.f;
            xout[(size_t)r * 32 + m]      = v0;
            xout[(size_t)r * 32 + m + 16] = v1;
        }
    }
}

// ---------------- K2: h = x @ gW^T, el/er — scalar-broadcast GEMM ----------------
// grid (ceil(N/256), 4 heads). gW/al/ar addresses are uniform (compile-time
// indices, uniform head) -> compiler scalarizes to s_load; x row lives in VGPRs.
// f32 math order identical to the round-0 version (bitwise-same outputs).
__global__ __launch_bounds__(256) void k_node(const float* __restrict__ x,
                                              const float* __restrict__ gW,
                                              const float* __restrict__ al,
                                              const float* __restrict__ ar,
                                              u16* __restrict__ hout,   // hcat + mod*128, row stride 384
                                              float* __restrict__ el,
                                              float* __restrict__ er){
    int head = blockIdx.y;
    int n = blockIdx.x * blockDim.x + threadIdx.x;
    int nc = n < NNODES ? n : NNODES - 1;   // tail threads duplicate last node (benign)
    float xr[32];
    const float4* xp = (const float4*)(x + (size_t)nc * 32);
    #pragma unroll
    for (int i = 0; i < 8; i++){
        float4 v = xp[i];
        xr[4*i] = v.x; xr[4*i+1] = v.y; xr[4*i+2] = v.z; xr[4*i+3] = v.w;
    }
    const float* wbase = gW + head * 1024;   // rows head*32 .. head*32+31
    const float* alh = al + head * 32;
    const float* arh = ar + head * 32;
    u16* hp = hout + (size_t)nc * COMBW + head * 32;
    float elv = 0.f, erv = 0.f;
    #pragma unroll
    for (int cg = 0; cg < 4; cg++){
        float acc[8];
        #pragma unroll
        for (int c = 0; c < 8; c++){
            const float* wr = wbase + (cg * 8 + c) * 32;
            float a = 0.f;
            #pragma unroll
            for (int k = 0; k < 32; k++) a += xr[k] * wr[k];
            acc[c] = a;
            elv += a * alh[cg * 8 + c];
            erv += a * arh[cg * 8 + c];
        }
        union { u16 s[8]; uint4 q; } u;
        #pragma unroll
        for (int c = 0; c < 8; c++) u.s[c] = f2b(acc[c]);
        *(uint4*)(hp + cg * 8) = u.q;
    }
    el[(size_t)nc * 4 + head] = elv;
    er[(size_t)nc * 4 + head] = erv;
}

// ---------------- K3: CSR build ----------------
__global__ void k_hist(const int* __restrict__ dst, int* __restrict__ cnt){
    int i = blockIdx.x * blockDim.x + threadIdx.x;
    if (i < NEDGES) atomicAdd(&cnt[dst[i]], 1);
}

__global__ __launch_bounds__(1024) void k_scan(const int* __restrict__ cnt, int* __restrict__ rp){
    __shared__ int wsum[16];
    int t = threadIdx.x, lane = t & 63, w = t >> 6;
    int carry = 0;
    for (int base = 0; base < NNODES; base += 1024){
        int v = (base + t < NNODES) ? cnt[base + t] : 0;
        int x = v;
        #pragma unroll
        for (int off = 1; off < 64; off <<= 1){
            int u = __shfl_up(x, off, 64);
            if (lane >= off) x += u;
        }
        if (lane == 63) wsum[w] = x;
        __syncthreads();
        if (w == 0){
            int s = (lane < 16) ? wsum[lane] : 0;
            #pragma unroll
            for (int off = 1; off < 16; off <<= 1){
                int u = __shfl_up(s, off, 64);
                if (lane >= off) s += u;
            }
            if (lane < 16) wsum[lane] = s;
        }
        __syncthreads();
        int woff = (w > 0) ? wsum[w - 1] : 0;
        if (base + t < NNODES) rp[base + t] = carry + woff + x - v;
        carry += wsum[15];
        __syncthreads();
    }
    if (t == 0) rp[NNODES] = carry;
}

// ---------------- K3b: CSR scatter, optionally fused with per-edge attention
// weights written in **CSR position order** (fixes the round-1 permutation bug:
// weight for CSR slot p must come from the original edge i that landed at p).
template<int WITHW>
__global__ __launch_bounds__(256) void k_scatter(const int* __restrict__ src, const int* __restrict__ dst,
                          const int* __restrict__ rp, int* __restrict__ fill,
                          int* __restrict__ col,
                          const float* __restrict__ el0, const float* __restrict__ er0,
                          const float* __restrict__ el1, const float* __restrict__ er1,
                          const float* __restrict__ el2, const float* __restrict__ er2,
                          float* __restrict__ w){
    int i = blockIdx.x * blockDim.x + threadIdx.x;
    if (i >= NEDGES) return;
    int s = src[i], d = dst[i];
    int p = rp[d] + atomicAdd(&fill[d], 1);
    col[p] = s;
    if (WITHW){
        float4 l0 = *(const float4*)(el0 + (size_t)s * 4);
        float4 r0 = *(const float4*)(er0 + (size_t)d * 4);
        float4 l1 = *(const float4*)(el1 + (size_t)s * 4);
        float4 r1 = *(const float4*)(er1 + (size_t)d * 4);
        float4 l2 = *(const float4*)(el2 + (size_t)s * 4);
        float4 r2 = *(const float4*)(er2 + (size_t)d * 4);
        float4 w0, w1, w2;
        #define LKEXP(a, b) __expf(fmaxf((a) + (b), 0.2f * ((a) + (b))))
        w0.x = LKEXP(l0.x, r0.x); w0.y = LKEXP(l0.y, r0.y); w0.z = LKEXP(l0.z, r0.z); w0.w = LKEXP(l0.w, r0.w);
        w1.x = LKEXP(l1.x, r1.x); w1.y = LKEXP(l1.y, r1.y); w1.z = LKEXP(l1.z, r1.z); w1.w = LKEXP(l1.w, r1.w);
        w2.x = LKEXP(l2.x, r2.x); w2.y = LKEXP(l2.y, r2.y); w2.z = LKEXP(l2.z, r2.z); w2.w = LKEXP(l2.w, r2.w);
        #undef LKEXP
        float4* wp = (float4*)(w + (size_t)p * 12);
        wp[0] = w0; wp[1] = w1; wp[2] = w2;
    }
}

// ---------------- K4: fused 3-modality GAT aggregation ----------
// PRE=1: weights precomputed (CSR order, broadcast loads). PRE=0: inline fallback.
template<int PRE>
__global__ __launch_bounds__(128) void k_gat(
        const int* __restrict__ rp, const int* __restrict__ col,
        const u16* __restrict__ hcat, const float* __restrict__ w,
        const float* __restrict__ el0, const float* __restrict__ er0,
        const float* __restrict__ el1, const float* __restrict__ er1,
        const float* __restrict__ el2, const float* __restrict__ er2,
        const float* __restrict__ gb0, const float* __restrict__ gb1, const float* __restrict__ gb2,
        u16* __restrict__ comb){
    int n = blockIdx.x, t = threadIdx.x;
    int head = t >> 5;
    float a0 = 0.f, a1 = 0.f, a2 = 0.f, d0 = 0.f, d1 = 0.f, d2 = 0.f;
    int beg = rp[n], end = rp[n + 1];
    if (PRE){
        const float* wp = w + (size_t)beg * 12 + head;
        for (int e = beg; e < end; e++, wp += 12){
            int s = col[e];
            const u16* hp = hcat + (size_t)s * COMBW + t;
            float w0 = wp[0], w1 = wp[4], w2 = wp[8];
            a0 += w0 * b2f(hp[0]);   d0 += w0;
            a1 += w1 * b2f(hp[128]); d1 += w1;
            a2 += w2 * b2f(hp[256]); d2 += w2;
        }
    } else {
        float e0 = er0[(size_t)n * 4 + head];
        float e1 = er1[(size_t)n * 4 + head];
        float e2 = er2[(size_t)n * 4 + head];
        for (int e = beg; e < end; e++){
            int s = col[e];
            const u16* hp = hcat + (size_t)s * COMBW + t;
            float v0 = el0[(size_t)s * 4 + head] + e0; v0 = fmaxf(v0, 0.2f * v0);
            float v1 = el1[(size_t)s * 4 + head] + e1; v1 = fmaxf(v1, 0.2f * v1);
            float v2 = el2[(size_t)s * 4 + head] + e2; v2 = fmaxf(v2, 0.2f * v2);
            float w0 = __expf(v0), w1 = __expf(v1), w2 = __expf(v2);
            a0 += w0 * b2f(hp[0]);   d0 += w0;
            a1 += w1 * b2f(hp[128]); d1 += w1;
            a2 += w2 * b2f(hp[256]); d2 += w2;
        }
    }
    size_t o = (size_t)n * COMBW;
    comb[o + t]       = f2b(a0 / fmaxf(d0, 1e-9f) + gb0[t]);
    comb[o + 128 + t] = f2b(a1 / fmaxf(d1, 1e-9f) + gb1[t]);
    comb[o + 256 + t] = f2b(a2 / fmaxf(d2, 1e-9f) + gb2[t]);
}

// ---------------- K5: out = relu(comb @ fcW^T + fcb), f32 out ----------------
__global__ __launch_bounds__(256) void k_fc(const u16* __restrict__ comb,
                                            const float* __restrict__ fcW,
                                            const float* __restrict__ fcb,
                                            float* __restrict__ out){
    int wave = threadIdx.x >> 6, lane = threadIdx.x & 63;
    int quad = lane >> 4, m = lane & 15;
    int row0 = blockIdx.x * 64 + wave * 16;
    int arow = row0 + m; if (arow >= NNODES) arow = NNODES - 1;
    const u16* ap = comb + (size_t)arow * COMBW + quad * 8;
    f32x4 c[8];
    #pragma unroll
    for (int f = 0; f < 8; f++) c[f] = (f32x4){0.f,0.f,0.f,0.f};
    for (int k = 0; k < COMBW; k += 32){
        bf16x8 a = *(const bf16x8*)(ap + k);
        #pragma unroll
        for (int f = 0; f < 8; f++){
            bf16x8 b = pack8(fcW + (size_t)(f * 16 + m) * COMBW + k + quad * 8);
            c[f] = __builtin_amdgcn_mfma_f32_16x16x32_bf16(a, b, c[f], 0, 0, 0);
        }
    }
    #pragma unroll
    for (int f = 0; f < 8; f++){
        int colc = f * 16 + m;
        float bv = fcb[colc];
        #pragma unroll
        for (int i = 0; i < 4; i++){
            int r = row0 + quad * 4 + i;
            if (r < NNODES){
                float v = c[f][i] + bv; v = v > 0.f ? v : 0.f;
                out[(size_t)(2 * NB * HD) + (size_t)r * HD + colc] = v;
            }
        }
    }
}

extern "C" void kernel_launch(void* const* d_in, const int* in_sizes, int n_in,
                              void* d_out, int out_size, void* d_ws, size_t ws_size,
                              hipStream_t stream){
    const int* uid = (const int*)d_in[0];
    const int* iid = (const int*)d_in[1];
    const int* src = (const int*)d_in[2];
    const int* dst = (const int*)d_in[3];
    const float* fimg = (const float*)d_in[4];
    const float* ftxt = (const float*)d_in[5];
    const float* faud = (const float*)d_in[6];
    const float* utab = (const float*)d_in[7];
    const float* itab = (const float*)d_in[8];
    const float* Wi = (const float*)d_in[9],  *bi = (const float*)d_in[10];
    const float* Wt = (const float*)d_in[11], *bt = (const float*)d_in[12];
    const float* Wa = (const float*)d_in[13], *ba = (const float*)d_in[14];
    const float* gWi = (const float*)d_in[15], *ali = (const float*)d_in[16],
               *ari = (const float*)d_in[17], *gbi = (const float*)d_in[18];
    const float* gWt = (const float*)d_in[19], *alt = (const float*)d_in[20],
               *art = (const float*)d_in[21], *gbt = (const float*)d_in[22];
    const float* gWa = (const float*)d_in[23], *ala = (const float*)d_in[24],
               *ara = (const float*)d_in[25], *gba = (const float*)d_in[26];
    const float* fcW = (const float*)d_in[27], *fcb = (const float*)d_in[28];
    float* out = (float*)d_out;

    char* ws = (char*)d_ws;
    u16*   hcat = (u16*)  (ws + 0);           // 38.4 MB  [n][3][128] interleaved
    u16*   comb = (u16*)  (ws + 38400000);    // 38.4 MB
    float* x    = (float*)(ws + 76800000);    // 6.4 MB (reused per modality)
    float* el   = (float*)(ws + 83200000);    // 3 x 800000 B
    float* er   = (float*)(ws + 85600000);    // 3 x 800000 B
    int*   cnt  = (int*)  (ws + 88000000);    // 200 KB
    int*   fill = (int*)  (ws + 88200000);    // 200 KB
    int*   rp   = (int*)  (ws + 88400000);    // 200 KB (+pad)
    int*   col  = (int*)  (ws + 88600064);    // 6.4 MB
    float* w    = (float*)(ws + 95000064);    // 76.8 MB (edge weights, CSR order, optional)
    const size_t NEED_W = 95000064u + (size_t)NEDGES * 12 * sizeof(float);

    float* el0 = el,           *el1 = el + 200000, *el2 = el + 400000;
    float* er0 = er,           *er1 = er + 200000, *er2 = er + 400000;

    hipMemsetAsync(cnt, 0, 400000, stream);   // cnt + fill (adjacent)

    // CSR histogram + scan (scatter deferred until el/er are ready)
    k_hist<<<(NEDGES + 255) / 256, 256, 0, stream>>>(dst, cnt);
    k_scan<<<1, 1024, 0, stream>>>(cnt, rp);

    // Embedding gathers straight to d_out
    k_gather<<<(2 * NB * HD / 8 + 255) / 256, 256, 0, stream>>>(uid, iid, utab, itab, out);

    // Modality pipelines (x buffer reused; stream-ordered)
    dim3 ngrid((NNODES + 255) / 256, 4);
    k_feat<<<(NNODES + 63) / 64, 256, 0, stream>>>(fimg, 1024, Wi, bi, x);
    k_node<<<ngrid, 256, 0, stream>>>(x, gWi, ali, ari, hcat,       el0, er0);
    k_feat<<<(NNODES + 63) / 64, 256, 0, stream>>>(ftxt, 768, Wt, bt, x);
    k_node<<<ngrid, 256, 0, stream>>>(x, gWt, alt, art, hcat + 128, el1, er1);
    k_feat<<<(NNODES + 63) / 64, 256, 0, stream>>>(faud, 128, Wa, ba, x);
    k_node<<<ngrid, 256, 0, stream>>>(x, gWa, ala, ara, hcat + 256, el2, er2);

    // Fused edge-softmax + aggregation for all 3 modalities
    if (ws_size >= NEED_W){
        k_scatter<1><<<(NEDGES + 255) / 256, 256, 0, stream>>>(src, dst, rp, fill, col,
                                                               el0, er0, el1, er1, el2, er2, w);
        k_gat<1><<<NNODES, 128, 0, stream>>>(rp, col, hcat, w,
                                             el0, er0, el1, er1, el2, er2,
                                             gbi, gbt, gba, comb);
    } else {
        k_scatter<0><<<(NEDGES + 255) / 256, 256, 0, stream>>>(src, dst, rp, fill, col,
                                                               el0, er0, el1, er1, el2, er2, w);
        k_gat<0><<<NNODES, 128, 0, stream>>>(rp, col, hcat, w,
                                             el0, er0, el1, er1, el2, er2,
                                             gbi, gbt, gba, comb);
    }

    // Final fc
    k_fc<<<(NNODES + 63) / 64, 256, 0, stream>>>(comb, fcW, fcb, out);
}